// Round 1
// baseline (95.508 us; speedup 1.0000x reference)
//
#include <hip/hip_runtime.h>
#include <hip/hip_bf16.h>

#define N_ROWS 4096
#define TWO_N  8192
#define ZDIM   256
#define INV_T  (1.0f/0.07f)
// exp((s-1)/T) = exp2((s-1) * INV_T * log2(e))
#define EXP_SCALE (INV_T * 1.44269504088896340736f)

typedef __attribute__((ext_vector_type(4))) float f32x4;
typedef __attribute__((ext_vector_type(8))) int   i32x8;
typedef __attribute__((ext_vector_type(2))) int   i32x2;

// Unit scale: E8M0 127 -> 2^0 in every byte, so any opsel byte-pick gives 1.0
#define SCALE_ONE 0x7F7F7F7F

__device__ __forceinline__ void async_load16(const void* g, void* lds_uniform_base) {
  // HW computes LDS dest = (wave-uniform base) + lane*16; pass base WITHOUT lane term.
  __builtin_amdgcn_global_load_lds(
      (const __attribute__((address_space(1))) void*)g,
      (__attribute__((address_space(3))) void*)lds_uniform_base, 16, 0, 0);
}

// float -> OCP e4m3fn, round-to-nearest-even. Inputs here are |x| <= 1.
__device__ __forceinline__ unsigned char f32_to_e4m3(float x) {
  unsigned int u = __float_as_uint(x);
  const unsigned int s = u >> 31;
  unsigned int a = u & 0x7FFFFFFFu;
  if (a > 0x43E00000u) a = 0x43E00000u;
  const float f = __uint_as_float(a);
  unsigned int out;
  if (a < (121u << 23)) {                        // |x| < 2^-6: subnormal, step 2^-9
    const int m = (int)rintf(f * 512.0f);
    out = (unsigned int)m;
  } else {
    const unsigned int r = a + 0x7FFFFu + ((a >> 20) & 1u);  // RNE to 3 mantissa bits
    const unsigned int e8 = (r >> 23) - 120u;
    out = (e8 << 3) | ((r >> 20) & 7u);
  }
  return (unsigned char)(out | (s << 7));
}

// ---------------- Kernel A: wave-per-row normalize -> fp8 reps, fp32 pos ---------------
// 1024 blocks x 4 waves: wave handles one row of z1 AND z2. float4 loads, uchar4 stores.
__global__ __launch_bounds__(256) void normalize_kernel(
    const float* __restrict__ z1, const float* __restrict__ z2,
    unsigned char* __restrict__ reps, float* __restrict__ pos,
    float* __restrict__ out) {
  const int lane = threadIdx.x & 63;
  const int wave = threadIdx.x >> 6;
  const int r = blockIdx.x * 4 + wave;
  const float4 a = ((const float4*)(z1 + (size_t)r * ZDIM))[lane];
  const float4 b = ((const float4*)(z2 + (size_t)r * ZDIM))[lane];
  float s1 = a.x*a.x + a.y*a.y + a.z*a.z + a.w*a.w;
  float s2 = b.x*b.x + b.y*b.y + b.z*b.z + b.w*b.w;
  float s3 = a.x*b.x + a.y*b.y + a.z*b.z + a.w*b.w;
  #pragma unroll
  for (int m = 1; m < 64; m <<= 1) {
    s1 += __shfl_xor(s1, m, 64);
    s2 += __shfl_xor(s2, m, 64);
    s3 += __shfl_xor(s3, m, 64);
  }
  const float inv1 = 1.0f / fmaxf(sqrtf(s1), 1e-12f);
  const float inv2 = 1.0f / fmaxf(sqrtf(s2), 1e-12f);
  uchar4 pa, pb;
  pa.x = f32_to_e4m3(a.x * inv1); pa.y = f32_to_e4m3(a.y * inv1);
  pa.z = f32_to_e4m3(a.z * inv1); pa.w = f32_to_e4m3(a.w * inv1);
  pb.x = f32_to_e4m3(b.x * inv2); pb.y = f32_to_e4m3(b.y * inv2);
  pb.z = f32_to_e4m3(b.z * inv2); pb.w = f32_to_e4m3(b.w * inv2);
  ((uchar4*)(reps + (size_t)r * ZDIM))[lane] = pa;
  ((uchar4*)(reps + (size_t)(r + N_ROWS) * ZDIM))[lane] = pb;
  if (lane == 0) {
    pos[r] = s3 * inv1 * inv2;
    if (r == 0) out[0] = INV_T;
  }
}

// ---------------- Kernel B: triangular fp8 flash, K=128 ping-pong pipelined staging -----
// sim symmetric: each unordered 128x128 tile-pair once. Row-tile i, chunk c in 0..7:
//   c==0: d={0(diag),1,2,3} (+32 if i<32); c>0: d={4c..4c+3}; j=(i+d)&63.
// B staged in K=128 halves into ping-pong buffers; stage(q+1) is issued BEFORE compute(q),
// so the vmcnt(0) drain at the barrier ending compute(q) waits on a load that has been in
// flight for the full MFMA pass — drain exposure ~0.
// Inner product: MX-scaled fp8 K=128 MFMA (unit scales) — 4661 TF rate vs 2047 for
// non-scaled 16x16x32, and 4x fewer MFMA instructions. Operand regs: register pair p of
// the i32x8 = the standard K=32 fp8 fragment of k-block p (scale byte per K=32 block),
// so the swizzled ds_read_b64 fetch pattern is IDENTICAL to the K=32 version.
// LDS 32K(A) + 2x16K(B) + 2K = 66KB -> 2 blocks/CU; grid (64,8)=512 = exactly 2/CU.
__global__ __launch_bounds__(256, 2) void simsum_kernel(
    const unsigned char* __restrict__ reps,
    float* __restrict__ rowscratch,   // [64][8][128]
    float* __restrict__ colscratch) { // [64][32][128]
  __shared__ __align__(16) unsigned char Alds[128 * 256];     // 32 KB
  __shared__ __align__(16) unsigned char Blds[2][128 * 128];  // 2 x 16 KB
  __shared__ float colred[2][256];                            // 2 KB

  const int tid  = threadIdx.x;
  const int lane = tid & 63;
  const int wave = tid >> 6;
  const int wm = wave >> 1, wn = wave & 1;   // 2x2 wave grid
  const int quad = lane >> 4;                // 0..3
  const int l16  = lane & 15;
  const int itile = blockIdx.x;              // row tile 0..63
  const int chunk = blockIdx.y;              // distance chunk 0..7
  const int rowBase = itile * 128;
  const char* gbase = (const char*)reps;
  const bool diaghere = (chunk == 0);

  // ---- stage A tile (once): rows [rowBase,+128), 256B/row = 16 16B-chunks.
  // LDS 16B-slot (row,k16) holds global k16' = (k16&8)|((k16^row)&7)  [XOR low3 swizzle]
  {
    const int r0 = tid >> 4;                                   // 0..15
    const int src = (tid & 8) | ((tid ^ (tid >> 4)) & 7);      // swizzled source chunk
    const char* g0 = gbase + (rowBase + r0) * ZDIM + src * 16; // +p*16 rows => +p*4096
    char* l0 = (char*)Alds + (wave << 10);                     // +p*4096
    #pragma unroll
    for (int p = 0; p < 8; ++p)
      async_load16(g0 + p * 16 * ZDIM, l0 + p * 4096);
  }

  int doff[4];
  int noff;
  if (diaghere) {
    doff[0] = 1; doff[1] = 2; doff[2] = 3; doff[3] = 32;
    noff = (itile < 32) ? 4 : 3;
  } else {
    doff[0] = chunk * 4; doff[1] = chunk * 4 + 1;
    doff[2] = chunk * 4 + 2; doff[3] = chunk * 4 + 3;
    noff = 4;
  }
  const int Q = noff * 2;   // stage/compute chunk-steps: tile t = q>>1, khalf c = q&1

  // stage B chunk q: rows [jt*128,+128), k in [c*128,+128). 128B/row = 8 16B-slots,
  // slot s holds global chunk s ^ (row&7).
#define STAGE_B(q_) do {                                                        \
    const int t_ = (q_) >> 1, c_ = (q_) & 1;                                    \
    const int jt_ = (itile + doff[t_]) & 63;                                    \
    const int r0_ = tid >> 3;                              /* 0..31 */          \
    const int src_ = (tid ^ (tid >> 3)) & 7;                                    \
    const char* g0_ = gbase + (jt_ * 128 + r0_) * ZDIM + c_ * 128 + src_ * 16;  \
    char* l0_ = (char*)Blds[c_] + (wave << 10);                                 \
    _Pragma("unroll")                                                           \
    for (int p_ = 0; p_ < 4; ++p_)                                              \
      async_load16(g0_ + p_ * 32 * ZDIM, l0_ + p_ * 4096);                      \
  } while (0)

  float rowpart[16];
  #pragma unroll
  for (int i = 0; i < 16; ++i) rowpart[i] = 0.0f;
  const f32x4 zero4 = {0.0f, 0.0f, 0.0f, 0.0f};

  // ---- prologue: diag tile (if any) computed while stage(0) is in flight ----
  if (diaghere) {
    __syncthreads();                  // drain A
    if (Q > 0) STAGE_B(0);            // covered by the diag compute below
    f32x4 acc[4][4];
    #pragma unroll
    for (int mi = 0; mi < 4; ++mi)
      #pragma unroll
      for (int ni = 0; ni < 4; ++ni) acc[mi][ni] = zero4;
    #pragma unroll
    for (int h = 0; h < 2; ++h) {     // 2 K=128 passes, both operands from Alds
      i32x8 afrag[4], bfrag[4];
      #pragma unroll
      for (int mi = 0; mi < 4; ++mi) {
        const int m = wm * 64 + mi * 16 + l16;
        #pragma unroll
        for (int ws = 0; ws < 4; ++ws) {
          const int o = h * 16 + ws * 4 + quad;   // global k-octet
          const int k16 = o >> 1, half = (o & 1) * 8;
          const int sw = (k16 & 8) | ((k16 ^ m) & 7);
          const i32x2 t = *(const i32x2*)((const char*)Alds + m * 256 + sw * 16 + half);
          afrag[mi][2 * ws] = t.x; afrag[mi][2 * ws + 1] = t.y;
        }
      }
      #pragma unroll
      for (int ni = 0; ni < 4; ++ni) {
        const int n = wn * 64 + ni * 16 + l16;
        #pragma unroll
        for (int ws = 0; ws < 4; ++ws) {
          const int o = h * 16 + ws * 4 + quad;
          const int k16 = o >> 1, half = (o & 1) * 8;
          const int sw = (k16 & 8) | ((k16 ^ n) & 7);
          const i32x2 t = *(const i32x2*)((const char*)Alds + n * 256 + sw * 16 + half);
          bfrag[ni][2 * ws] = t.x; bfrag[ni][2 * ws + 1] = t.y;
        }
      }
      #pragma unroll
      for (int mi = 0; mi < 4; ++mi)
        #pragma unroll
        for (int ni = 0; ni < 4; ++ni)
          acc[mi][ni] = __builtin_amdgcn_mfma_scale_f32_16x16x128_f8f6f4(
              afrag[mi], bfrag[ni], acc[mi][ni], 0, 0,
              0, SCALE_ONE, 0, SCALE_ONE);
    }
    // diag epilogue: rows only, self-masked (regs only, no LDS, no barrier)
    #pragma unroll
    for (int mi = 0; mi < 4; ++mi)
      #pragma unroll
      for (int r = 0; r < 4; ++r) {
        const int grow = rowBase + wm * 64 + mi * 16 + quad * 4 + r;
        float s = 0.0f;
        #pragma unroll
        for (int ni = 0; ni < 4; ++ni) {
          const int gcol = rowBase + wn * 64 + ni * 16 + l16;
          const float e = exp2f((acc[mi][ni][r] - 1.0f) * EXP_SCALE);
          if (grow != gcol) s += e;
        }
        rowpart[mi * 4 + r] += s;
      }
    __syncthreads();                  // drain stage(0)
  } else {
    STAGE_B(0);
    __syncthreads();                  // drain A + stage(0)
  }

  // ---- pipelined main loop over chunk-steps ----
  f32x4 acc[4][4];
  for (int q = 0; q < Q; ++q) {
    if (q + 1 < Q) STAGE_B(q + 1);    // in flight during compute(q)
    const int t = q >> 1, c = q & 1;
    const int d = doff[t];
    const int jtile = (itile + d) & 63;
    const int colBase = jtile * 128;
    (void)colBase;

    if (c == 0) {
      #pragma unroll
      for (int mi = 0; mi < 4; ++mi)
        #pragma unroll
        for (int ni = 0; ni < 4; ++ni) acc[mi][ni] = zero4;
    }
    // one K=128 scaled-MFMA pass for this half
    {
      i32x8 afrag[4], bfrag[4];
      #pragma unroll
      for (int mi = 0; mi < 4; ++mi) {
        const int m = wm * 64 + mi * 16 + l16;
        #pragma unroll
        for (int ws = 0; ws < 4; ++ws) {
          const int o = c * 16 + ws * 4 + quad;   // global k-octet
          const int k16 = o >> 1, half = (o & 1) * 8;
          const int sw = (k16 & 8) | ((k16 ^ m) & 7);
          const i32x2 t = *(const i32x2*)((const char*)Alds + m * 256 + sw * 16 + half);
          afrag[mi][2 * ws] = t.x; afrag[mi][2 * ws + 1] = t.y;
        }
      }
      #pragma unroll
      for (int ni = 0; ni < 4; ++ni) {
        const int n = wn * 64 + ni * 16 + l16;
        #pragma unroll
        for (int ws = 0; ws < 4; ++ws) {
          const int ol = ws * 4 + quad;           // chunk-local octet
          const int k16l = ol >> 1, halfl = (ol & 1) * 8;
          const int sw = (k16l ^ n) & 7;
          const i32x2 t = *(const i32x2*)((const char*)Blds[c] + n * 128 + sw * 16 + halfl);
          bfrag[ni][2 * ws] = t.x; bfrag[ni][2 * ws + 1] = t.y;
        }
      }
      #pragma unroll
      for (int mi = 0; mi < 4; ++mi)
        #pragma unroll
        for (int ni = 0; ni < 4; ++ni)
          acc[mi][ni] = __builtin_amdgcn_mfma_scale_f32_16x16x128_f8f6f4(
              afrag[mi], bfrag[ni], acc[mi][ni], 0, 0,
              0, SCALE_ONE, 0, SCALE_ONE);
    }

    if (c == 1) {
      // tile complete: exp epilogue. Rows -> rowpart; cols -> colred[t&1] -> colscratch.
      float colpart[4] = {0.0f, 0.0f, 0.0f, 0.0f};
      #pragma unroll
      for (int mi = 0; mi < 4; ++mi)
        #pragma unroll
        for (int r = 0; r < 4; ++r) {
          float s = 0.0f;
          #pragma unroll
          for (int ni = 0; ni < 4; ++ni) {
            const float e = exp2f((acc[mi][ni][r] - 1.0f) * EXP_SCALE);
            s += e;
            colpart[ni] += e;
          }
          rowpart[mi * 4 + r] += s;
        }
      #pragma unroll
      for (int ni = 0; ni < 4; ++ni) {
        float v = colpart[ni];
        v += __shfl_xor(v, 16, 64);   // reduce across the 4 quads (frag rows)
        v += __shfl_xor(v, 32, 64);
        if (quad == 0) colred[t & 1][wm * 128 + wn * 64 + ni * 16 + l16] = v;
      }
      __syncthreads();   // drains stage(q+1) [in flight all of compute(q)]; colred visible
      if (tid < 128)
        colscratch[(jtile * 32 + (d - 1)) * 128 + tid] =
            colred[t & 1][tid] + colred[t & 1][128 + tid];
      // next write to colred[t&1] is 2 barriers away (tile t+2) — safe without barrier
    } else {
      __syncthreads();   // drains stage(q+1); frees Blds[0] for stage(q+2)
    }
  }

  // ---- row partials: shfl over 16 col-lanes, merge wn-halves via LDS (they cover the
  // SAME rows — per-wave plain stores would race), one store per row ----
  #pragma unroll
  for (int i = 0; i < 16; ++i) {
    float v = rowpart[i];
    v += __shfl_xor(v, 1, 64);
    v += __shfl_xor(v, 2, 64);
    v += __shfl_xor(v, 4, 64);
    v += __shfl_xor(v, 8, 64);
    rowpart[i] = v;
  }
  __syncthreads();
  if (l16 == 0) {
    #pragma unroll
    for (int mi = 0; mi < 4; ++mi)
      #pragma unroll
      for (int r = 0; r < 4; ++r)
        colred[0][wn * 128 + wm * 64 + mi * 16 + quad * 4 + r] = rowpart[mi * 4 + r];
  }
  __syncthreads();
  if (tid < 128)
    rowscratch[(itile * 8 + chunk) * 128 + tid] = colred[0][tid] + colred[0][128 + tid];
#undef STAGE_B
}

// ---------------- Kernel C: gather partials per row, logf, add partial loss -------------
__global__ __launch_bounds__(256) void reduce_kernel(
    const float* __restrict__ rowscratch, const float* __restrict__ colscratch,
    const float* __restrict__ pos, float* __restrict__ out) {
  const int j = blockIdx.x;
  const int tid = threadIdx.x;
  float v = 0.0f;
  if (tid < 128) {
    float s = 0.0f;
    #pragma unroll
    for (int c = 0; c < 8; ++c) s += rowscratch[(j * 8 + c) * 128 + tid];
    const int ns = (j < 32) ? 31 : 32;   // j<32: the d=32 pair arrived via rowscratch side
    for (int si = 0; si < ns; ++si) s += colscratch[(j * 32 + si) * 128 + tid];
    v = logf(s) * (1.0f / (float)TWO_N);
  } else if (tid < 192) {
    v = -pos[j * 64 + (tid - 128)] * (INV_T / (float)N_ROWS);
  }
  #pragma unroll
  for (int m = 1; m < 64; m <<= 1) v += __shfl_xor(v, m, 64);
  __shared__ float red[4];
  if ((tid & 63) == 0) red[tid >> 6] = v;
  __syncthreads();
  if (tid == 0) atomicAdd(out, red[0] + red[1] + red[2] + red[3]);
}

extern "C" void kernel_launch(void* const* d_in, const int* in_sizes, int n_in,
                              void* d_out, int out_size, void* d_ws, size_t ws_size,
                              hipStream_t stream) {
  const float* z1 = (const float*)d_in[0];
  const float* z2 = (const float*)d_in[1];
  char* ws = (char*)d_ws;
  unsigned char* reps = (unsigned char*)ws;                // 8192*256 = 2 MB fp8
  size_t off = (size_t)TWO_N * ZDIM;
  float* pos = (float*)(ws + off);        off += N_ROWS * 4;        // 16 KB
  float* rowscratch = (float*)(ws + off); off += 64 * 8 * 128 * 4;  // 256 KB
  float* colscratch = (float*)(ws + off); off += 64 * 32 * 128 * 4; // 1 MB

  normalize_kernel<<<1024, 256, 0, stream>>>(z1, z2, reps, pos, (float*)d_out);
  simsum_kernel<<<dim3(64, 8), 256, 0, stream>>>(reps, rowscratch, colscratch);
  reduce_kernel<<<64, 256, 0, stream>>>(rowscratch, colscratch, pos, (float*)d_out);
}

// Round 2
// 94.962 us; speedup vs baseline: 1.0057x; 1.0057x over previous
//
#include <hip/hip_runtime.h>
#include <hip/hip_bf16.h>

#define N_ROWS 4096
#define TWO_N  8192
#define ZDIM   256
#define INV_T  (1.0f/0.07f)
// exp((s-1)/T) = exp2((s-1) * INV_T * log2(e))
#define EXP_SCALE (INV_T * 1.44269504088896340736f)

typedef __attribute__((ext_vector_type(4))) float f32x4;
typedef __attribute__((ext_vector_type(8))) int   i32x8;
typedef __attribute__((ext_vector_type(2))) int   i32x2;

// Unit scale: E8M0 127 -> 2^0 in every byte, so any opsel byte-pick gives 1.0
#define SCALE_ONE 0x7F7F7F7F

__device__ __forceinline__ void async_load16(const void* g, void* lds_uniform_base) {
  // HW computes LDS dest = (wave-uniform base) + lane*16; pass base WITHOUT lane term.
  __builtin_amdgcn_global_load_lds(
      (const __attribute__((address_space(1))) void*)g,
      (__attribute__((address_space(3))) void*)lds_uniform_base, 16, 0, 0);
}

// float -> OCP e4m3fn, round-to-nearest-even. Inputs here are |x| <= 1.
__device__ __forceinline__ unsigned char f32_to_e4m3(float x) {
  unsigned int u = __float_as_uint(x);
  const unsigned int s = u >> 31;
  unsigned int a = u & 0x7FFFFFFFu;
  if (a > 0x43E00000u) a = 0x43E00000u;
  const float f = __uint_as_float(a);
  unsigned int out;
  if (a < (121u << 23)) {                        // |x| < 2^-6: subnormal, step 2^-9
    const int m = (int)rintf(f * 512.0f);
    out = (unsigned int)m;
  } else {
    const unsigned int r = a + 0x7FFFFu + ((a >> 20) & 1u);  // RNE to 3 mantissa bits
    const unsigned int e8 = (r >> 23) - 120u;
    out = (e8 << 3) | ((r >> 20) & 7u);
  }
  return (unsigned char)(out | (s << 7));
}

// ---------------- Kernel A: wave-per-row normalize -> fp8 reps, fp32 pos ---------------
// 1024 blocks x 4 waves: wave handles one row of z1 AND z2. float4 loads, uchar4 stores.
__global__ __launch_bounds__(256) void normalize_kernel(
    const float* __restrict__ z1, const float* __restrict__ z2,
    unsigned char* __restrict__ reps, float* __restrict__ pos,
    float* __restrict__ out) {
  const int lane = threadIdx.x & 63;
  const int wave = threadIdx.x >> 6;
  const int r = blockIdx.x * 4 + wave;
  const float4 a = ((const float4*)(z1 + (size_t)r * ZDIM))[lane];
  const float4 b = ((const float4*)(z2 + (size_t)r * ZDIM))[lane];
  float s1 = a.x*a.x + a.y*a.y + a.z*a.z + a.w*a.w;
  float s2 = b.x*b.x + b.y*b.y + b.z*b.z + b.w*b.w;
  float s3 = a.x*b.x + a.y*b.y + a.z*b.z + a.w*b.w;
  #pragma unroll
  for (int m = 1; m < 64; m <<= 1) {
    s1 += __shfl_xor(s1, m, 64);
    s2 += __shfl_xor(s2, m, 64);
    s3 += __shfl_xor(s3, m, 64);
  }
  const float inv1 = 1.0f / fmaxf(sqrtf(s1), 1e-12f);
  const float inv2 = 1.0f / fmaxf(sqrtf(s2), 1e-12f);
  uchar4 pa, pb;
  pa.x = f32_to_e4m3(a.x * inv1); pa.y = f32_to_e4m3(a.y * inv1);
  pa.z = f32_to_e4m3(a.z * inv1); pa.w = f32_to_e4m3(a.w * inv1);
  pb.x = f32_to_e4m3(b.x * inv2); pb.y = f32_to_e4m3(b.y * inv2);
  pb.z = f32_to_e4m3(b.z * inv2); pb.w = f32_to_e4m3(b.w * inv2);
  ((uchar4*)(reps + (size_t)r * ZDIM))[lane] = pa;
  ((uchar4*)(reps + (size_t)(r + N_ROWS) * ZDIM))[lane] = pb;
  if (lane == 0) {
    pos[r] = s3 * inv1 * inv2;
    if (r == 0) out[0] = INV_T;
  }
}

// ---------------- Kernel B: triangular fp8 flash, K=128 ping-pong pipelined staging -----
// sim symmetric: each unordered 128x128 tile-pair once. Row-tile i, chunk c in 0..7:
//   c==0: d={0(diag),1,2,3} (+32 if i<32); c>0: d={4c..4c+3}; j=(i+d)&63.
// B staged in K=128 halves into ping-pong buffers; stage(q+1) is issued BEFORE compute(q),
// so the vmcnt(0) drain at the barrier ending compute(q) waits on a load that has been in
// flight for the full MFMA pass — drain exposure ~0.
// Inner product: MX-scaled fp8 K=128 MFMA (unit scales) — 4661 TF rate vs 2047 for
// non-scaled 16x16x32, and 4x fewer MFMA instructions. Operand regs: register pair p of
// the i32x8 = the standard K=32 fp8 fragment of k-block p (scale byte per K=32 block),
// so the swizzled ds_read_b64 fetch pattern is IDENTICAL to the K=32 version.
// LDS 32K(A) + 2x16K(B) + 2K = 66KB -> 2 blocks/CU; grid (64,8)=512 = exactly 2/CU.
__global__ __launch_bounds__(256, 2) void simsum_kernel(
    const unsigned char* __restrict__ reps,
    float* __restrict__ rowscratch,   // [64][8][128]
    float* __restrict__ colscratch) { // [64][32][128]
  __shared__ __align__(16) unsigned char Alds[128 * 256];     // 32 KB
  __shared__ __align__(16) unsigned char Blds[2][128 * 128];  // 2 x 16 KB
  __shared__ float colred[2][256];                            // 2 KB

  const int tid  = threadIdx.x;
  const int lane = tid & 63;
  const int wave = tid >> 6;
  const int wm = wave >> 1, wn = wave & 1;   // 2x2 wave grid
  const int quad = lane >> 4;                // 0..3
  const int l16  = lane & 15;
  const int itile = blockIdx.x;              // row tile 0..63
  const int chunk = blockIdx.y;              // distance chunk 0..7
  const int rowBase = itile * 128;
  const char* gbase = (const char*)reps;
  const bool diaghere = (chunk == 0);

  // ---- stage A tile (once): rows [rowBase,+128), 256B/row = 16 16B-chunks.
  // LDS 16B-slot (row,k16) holds global k16' = (k16&8)|((k16^row)&7)  [XOR low3 swizzle]
  {
    const int r0 = tid >> 4;                                   // 0..15
    const int src = (tid & 8) | ((tid ^ (tid >> 4)) & 7);      // swizzled source chunk
    const char* g0 = gbase + (rowBase + r0) * ZDIM + src * 16; // +p*16 rows => +p*4096
    char* l0 = (char*)Alds + (wave << 10);                     // +p*4096
    #pragma unroll
    for (int p = 0; p < 8; ++p)
      async_load16(g0 + p * 16 * ZDIM, l0 + p * 4096);
  }

  int doff[4];
  int noff;
  if (diaghere) {
    doff[0] = 1; doff[1] = 2; doff[2] = 3; doff[3] = 32;
    noff = (itile < 32) ? 4 : 3;
  } else {
    doff[0] = chunk * 4; doff[1] = chunk * 4 + 1;
    doff[2] = chunk * 4 + 2; doff[3] = chunk * 4 + 3;
    noff = 4;
  }
  const int Q = noff * 2;   // stage/compute chunk-steps: tile t = q>>1, khalf c = q&1

  // stage B chunk q: rows [jt*128,+128), k in [c*128,+128). 128B/row = 8 16B-slots,
  // slot s holds global chunk s ^ (row&7).
#define STAGE_B(q_) do {                                                        \
    const int t_ = (q_) >> 1, c_ = (q_) & 1;                                    \
    const int jt_ = (itile + doff[t_]) & 63;                                    \
    const int r0_ = tid >> 3;                              /* 0..31 */          \
    const int src_ = (tid ^ (tid >> 3)) & 7;                                    \
    const char* g0_ = gbase + (jt_ * 128 + r0_) * ZDIM + c_ * 128 + src_ * 16;  \
    char* l0_ = (char*)Blds[c_] + (wave << 10);                                 \
    _Pragma("unroll")                                                           \
    for (int p_ = 0; p_ < 4; ++p_)                                              \
      async_load16(g0_ + p_ * 32 * ZDIM, l0_ + p_ * 4096);                      \
  } while (0)

  float rowpart[16];
  #pragma unroll
  for (int i = 0; i < 16; ++i) rowpart[i] = 0.0f;
  const f32x4 zero4 = {0.0f, 0.0f, 0.0f, 0.0f};

  // ---- prologue: diag tile (if any) computed while stage(0) is in flight ----
  if (diaghere) {
    __syncthreads();                  // drain A
    if (Q > 0) STAGE_B(0);            // covered by the diag compute below
    f32x4 acc[4][4];
    #pragma unroll
    for (int mi = 0; mi < 4; ++mi)
      #pragma unroll
      for (int ni = 0; ni < 4; ++ni) acc[mi][ni] = zero4;
    #pragma unroll
    for (int h = 0; h < 2; ++h) {     // 2 K=128 passes, both operands from Alds
      i32x8 afrag[4], bfrag[4];
      #pragma unroll
      for (int mi = 0; mi < 4; ++mi) {
        const int m = wm * 64 + mi * 16 + l16;
        #pragma unroll
        for (int ws = 0; ws < 4; ++ws) {
          const int o = h * 16 + ws * 4 + quad;   // global k-octet
          const int k16 = o >> 1, half = (o & 1) * 8;
          const int sw = (k16 & 8) | ((k16 ^ m) & 7);
          const i32x2 t = *(const i32x2*)((const char*)Alds + m * 256 + sw * 16 + half);
          afrag[mi][2 * ws] = t.x; afrag[mi][2 * ws + 1] = t.y;
        }
      }
      #pragma unroll
      for (int ni = 0; ni < 4; ++ni) {
        const int n = wn * 64 + ni * 16 + l16;
        #pragma unroll
        for (int ws = 0; ws < 4; ++ws) {
          const int o = h * 16 + ws * 4 + quad;
          const int k16 = o >> 1, half = (o & 1) * 8;
          const int sw = (k16 & 8) | ((k16 ^ n) & 7);
          const i32x2 t = *(const i32x2*)((const char*)Alds + n * 256 + sw * 16 + half);
          bfrag[ni][2 * ws] = t.x; bfrag[ni][2 * ws + 1] = t.y;
        }
      }
      #pragma unroll
      for (int mi = 0; mi < 4; ++mi)
        #pragma unroll
        for (int ni = 0; ni < 4; ++ni)
          acc[mi][ni] = __builtin_amdgcn_mfma_scale_f32_16x16x128_f8f6f4(
              afrag[mi], bfrag[ni], acc[mi][ni], 0, 0,
              0, SCALE_ONE, 0, SCALE_ONE);
    }
    // diag epilogue: rows only, self-masked (regs only, no LDS, no barrier)
    #pragma unroll
    for (int mi = 0; mi < 4; ++mi)
      #pragma unroll
      for (int r = 0; r < 4; ++r) {
        const int grow = rowBase + wm * 64 + mi * 16 + quad * 4 + r;
        float s = 0.0f;
        #pragma unroll
        for (int ni = 0; ni < 4; ++ni) {
          const int gcol = rowBase + wn * 64 + ni * 16 + l16;
          const float e = exp2f((acc[mi][ni][r] - 1.0f) * EXP_SCALE);
          if (grow != gcol) s += e;
        }
        rowpart[mi * 4 + r] += s;
      }
    __syncthreads();                  // drain stage(0)
  } else {
    STAGE_B(0);
    __syncthreads();                  // drain A + stage(0)
  }

  // ---- pipelined main loop over chunk-steps ----
  f32x4 acc[4][4];
  for (int q = 0; q < Q; ++q) {
    if (q + 1 < Q) STAGE_B(q + 1);    // in flight during compute(q)
    const int t = q >> 1, c = q & 1;
    const int d = doff[t];
    const int jtile = (itile + d) & 63;

    if (c == 0) {
      #pragma unroll
      for (int mi = 0; mi < 4; ++mi)
        #pragma unroll
        for (int ni = 0; ni < 4; ++ni) acc[mi][ni] = zero4;
    }
    // one K=128 scaled-MFMA pass for this half
    {
      i32x8 afrag[4], bfrag[4];
      #pragma unroll
      for (int mi = 0; mi < 4; ++mi) {
        const int m = wm * 64 + mi * 16 + l16;
        #pragma unroll
        for (int ws = 0; ws < 4; ++ws) {
          const int o = c * 16 + ws * 4 + quad;   // global k-octet
          const int k16 = o >> 1, half = (o & 1) * 8;
          const int sw = (k16 & 8) | ((k16 ^ m) & 7);
          const i32x2 t = *(const i32x2*)((const char*)Alds + m * 256 + sw * 16 + half);
          afrag[mi][2 * ws] = t.x; afrag[mi][2 * ws + 1] = t.y;
        }
      }
      #pragma unroll
      for (int ni = 0; ni < 4; ++ni) {
        const int n = wn * 64 + ni * 16 + l16;
        #pragma unroll
        for (int ws = 0; ws < 4; ++ws) {
          const int ol = ws * 4 + quad;           // chunk-local octet
          const int k16l = ol >> 1, halfl = (ol & 1) * 8;
          const int sw = (k16l ^ n) & 7;
          const i32x2 t = *(const i32x2*)((const char*)Blds[c] + n * 128 + sw * 16 + halfl);
          bfrag[ni][2 * ws] = t.x; bfrag[ni][2 * ws + 1] = t.y;
        }
      }
      #pragma unroll
      for (int mi = 0; mi < 4; ++mi)
        #pragma unroll
        for (int ni = 0; ni < 4; ++ni)
          acc[mi][ni] = __builtin_amdgcn_mfma_scale_f32_16x16x128_f8f6f4(
              afrag[mi], bfrag[ni], acc[mi][ni], 0, 0,
              0, SCALE_ONE, 0, SCALE_ONE);
    }

    if (c == 1) {
      // tile complete: exp epilogue. Rows -> rowpart; cols -> colred[t&1] -> colscratch.
      float colpart[4] = {0.0f, 0.0f, 0.0f, 0.0f};
      #pragma unroll
      for (int mi = 0; mi < 4; ++mi)
        #pragma unroll
        for (int r = 0; r < 4; ++r) {
          float s = 0.0f;
          #pragma unroll
          for (int ni = 0; ni < 4; ++ni) {
            const float e = exp2f((acc[mi][ni][r] - 1.0f) * EXP_SCALE);
            s += e;
            colpart[ni] += e;
          }
          rowpart[mi * 4 + r] += s;
        }
      #pragma unroll
      for (int ni = 0; ni < 4; ++ni) {
        float v = colpart[ni];
        v += __shfl_xor(v, 16, 64);   // reduce across the 4 quads (frag rows)
        v += __shfl_xor(v, 32, 64);
        if (quad == 0) colred[t & 1][wm * 128 + wn * 64 + ni * 16 + l16] = v;
      }
      __syncthreads();   // drains stage(q+1) [in flight all of compute(q)]; colred visible
      if (tid < 128)
        colscratch[(jtile * 32 + (d - 1)) * 128 + tid] =
            colred[t & 1][tid] + colred[t & 1][128 + tid];
      // next write to colred[t&1] is 2 barriers away (tile t+2) — safe without barrier
    } else {
      __syncthreads();   // drains stage(q+1); frees Blds[0] for stage(q+2)
    }
  }

  // ---- row partials: shfl over 16 col-lanes, merge wn-halves via LDS (they cover the
  // SAME rows — per-wave plain stores would race), one store per row ----
  #pragma unroll
  for (int i = 0; i < 16; ++i) {
    float v = rowpart[i];
    v += __shfl_xor(v, 1, 64);
    v += __shfl_xor(v, 2, 64);
    v += __shfl_xor(v, 4, 64);
    v += __shfl_xor(v, 8, 64);
    rowpart[i] = v;
  }
  __syncthreads();
  if (l16 == 0) {
    #pragma unroll
    for (int mi = 0; mi < 4; ++mi)
      #pragma unroll
      for (int r = 0; r < 4; ++r)
        colred[0][wn * 128 + wm * 64 + mi * 16 + quad * 4 + r] = rowpart[mi * 4 + r];
  }
  __syncthreads();
  if (tid < 128)
    rowscratch[(itile * 8 + chunk) * 128 + tid] = colred[0][tid] + colred[0][128 + tid];
#undef STAGE_B
}

// ---------------- Kernel C: fully-parallel gather of row partials --------------------
// 512 blocks x 256 threads: 16 rows/block, 16 lanes/row, each lane loads <=3 partials
// (fully unrolled, independent loads), 4-step shfl reduce per row, log, block reduce.
// Replaces the 64-block version whose runtime-bounded 32-iteration serial gather loop
// was latency-bound at 25% CU coverage.
__global__ __launch_bounds__(256) void reduce_kernel(
    const float* __restrict__ rowscratch, const float* __restrict__ colscratch,
    const float* __restrict__ pos, float* __restrict__ out) {
  const int bid = blockIdx.x;              // 0..511
  const int tid = threadIdx.x;
  const int j  = bid * 16 + (tid >> 4);    // global row 0..8191 (16 rows share one jt)
  const int k  = tid & 15;                 // slice within row
  const int jt = j >> 7, o = j & 127;
  const int ns = (jt < 32) ? 31 : 32;      // jt<32: d=32 pair arrived via rowscratch side
  const int limit = 8 + ns;                // 39 or 40 partials per row
  float s = 0.0f;
  #pragma unroll
  for (int step = 0; step < 3; ++step) {
    const int idx = k + step * 16;
    if (idx < limit)
      s += (idx < 8) ? rowscratch[(jt * 8 + idx) * 128 + o]
                     : colscratch[(jt * 32 + (idx - 8)) * 128 + o];
  }
  s += __shfl_xor(s, 1, 64);
  s += __shfl_xor(s, 2, 64);
  s += __shfl_xor(s, 4, 64);
  s += __shfl_xor(s, 8, 64);               // all 16 lanes of the group now hold row sum
  float v = (k == 0) ? logf(s) * (1.0f / (float)TWO_N) : 0.0f;
  if (tid < 8) v -= pos[bid * 8 + tid] * (INV_T / (float)N_ROWS);
  #pragma unroll
  for (int m = 1; m < 64; m <<= 1) v += __shfl_xor(v, m, 64);
  __shared__ float red[4];
  if ((tid & 63) == 0) red[tid >> 6] = v;
  __syncthreads();
  if (tid == 0) atomicAdd(out, red[0] + red[1] + red[2] + red[3]);
}

extern "C" void kernel_launch(void* const* d_in, const int* in_sizes, int n_in,
                              void* d_out, int out_size, void* d_ws, size_t ws_size,
                              hipStream_t stream) {
  const float* z1 = (const float*)d_in[0];
  const float* z2 = (const float*)d_in[1];
  char* ws = (char*)d_ws;
  unsigned char* reps = (unsigned char*)ws;                // 8192*256 = 2 MB fp8
  size_t off = (size_t)TWO_N * ZDIM;
  float* pos = (float*)(ws + off);        off += N_ROWS * 4;        // 16 KB
  float* rowscratch = (float*)(ws + off); off += 64 * 8 * 128 * 4;  // 256 KB
  float* colscratch = (float*)(ws + off); off += 64 * 32 * 128 * 4; // 1 MB

  normalize_kernel<<<1024, 256, 0, stream>>>(z1, z2, reps, pos, (float*)d_out);
  simsum_kernel<<<dim3(64, 8), 256, 0, stream>>>(reps, rowscratch, colscratch);
  reduce_kernel<<<512, 256, 0, stream>>>(rowscratch, colscratch, pos, (float*)d_out);
}

// Round 3
// 93.723 us; speedup vs baseline: 1.0190x; 1.0132x over previous
//
#include <hip/hip_runtime.h>
#include <hip/hip_bf16.h>

#define N_ROWS 4096
#define TWO_N  8192
#define ZDIM   256
#define INV_T  (1.0f/0.07f)
// exp((s-1)/T) = exp2((s-1) * INV_T * log2(e))
#define EXP_SCALE (INV_T * 1.44269504088896340736f)

typedef __attribute__((ext_vector_type(4))) float f32x4;
typedef __attribute__((ext_vector_type(8))) int   i32x8;
typedef __attribute__((ext_vector_type(2))) int   i32x2;

// Unit scale: E8M0 127 -> 2^0 in every byte, so any opsel byte-pick gives 1.0
#define SCALE_ONE 0x7F7F7F7F

__device__ __forceinline__ void async_load16(const void* g, void* lds_uniform_base) {
  // HW computes LDS dest = (wave-uniform base) + lane*16; pass base WITHOUT lane term.
  __builtin_amdgcn_global_load_lds(
      (const __attribute__((address_space(1))) void*)g,
      (__attribute__((address_space(3))) void*)lds_uniform_base, 16, 0, 0);
}

// float -> OCP e4m3fn, round-to-nearest-even. Inputs here are |x| <= 1.
__device__ __forceinline__ unsigned char f32_to_e4m3(float x) {
  unsigned int u = __float_as_uint(x);
  const unsigned int s = u >> 31;
  unsigned int a = u & 0x7FFFFFFFu;
  if (a > 0x43E00000u) a = 0x43E00000u;
  const float f = __uint_as_float(a);
  unsigned int out;
  if (a < (121u << 23)) {                        // |x| < 2^-6: subnormal, step 2^-9
    const int m = (int)rintf(f * 512.0f);
    out = (unsigned int)m;
  } else {
    const unsigned int r = a + 0x7FFFFu + ((a >> 20) & 1u);  // RNE to 3 mantissa bits
    const unsigned int e8 = (r >> 23) - 120u;
    out = (e8 << 3) | ((r >> 20) & 7u);
  }
  return (unsigned char)(out | (s << 7));
}

// ---------------- Kernel A: wave-per-row normalize -> fp8 reps, fp32 pos ---------------
__global__ __launch_bounds__(256) void normalize_kernel(
    const float* __restrict__ z1, const float* __restrict__ z2,
    unsigned char* __restrict__ reps, float* __restrict__ pos,
    float* __restrict__ out) {
  const int lane = threadIdx.x & 63;
  const int wave = threadIdx.x >> 6;
  const int r = blockIdx.x * 4 + wave;
  const float4 a = ((const float4*)(z1 + (size_t)r * ZDIM))[lane];
  const float4 b = ((const float4*)(z2 + (size_t)r * ZDIM))[lane];
  float s1 = a.x*a.x + a.y*a.y + a.z*a.z + a.w*a.w;
  float s2 = b.x*b.x + b.y*b.y + b.z*b.z + b.w*b.w;
  float s3 = a.x*b.x + a.y*b.y + a.z*b.z + a.w*b.w;
  #pragma unroll
  for (int m = 1; m < 64; m <<= 1) {
    s1 += __shfl_xor(s1, m, 64);
    s2 += __shfl_xor(s2, m, 64);
    s3 += __shfl_xor(s3, m, 64);
  }
  const float inv1 = 1.0f / fmaxf(sqrtf(s1), 1e-12f);
  const float inv2 = 1.0f / fmaxf(sqrtf(s2), 1e-12f);
  uchar4 pa, pb;
  pa.x = f32_to_e4m3(a.x * inv1); pa.y = f32_to_e4m3(a.y * inv1);
  pa.z = f32_to_e4m3(a.z * inv1); pa.w = f32_to_e4m3(a.w * inv1);
  pb.x = f32_to_e4m3(b.x * inv2); pb.y = f32_to_e4m3(b.y * inv2);
  pb.z = f32_to_e4m3(b.z * inv2); pb.w = f32_to_e4m3(b.w * inv2);
  ((uchar4*)(reps + (size_t)r * ZDIM))[lane] = pa;
  ((uchar4*)(reps + (size_t)(r + N_ROWS) * ZDIM))[lane] = pb;
  if (lane == 0) {
    pos[r] = s3 * inv1 * inv2;
    if (r == 0) out[0] = INV_T;
  }
}

// ---------------- Kernel B: triangular fp8 flash, A held in registers ------------------
// sim symmetric: each unordered 128x128 tile-pair once. Row-tile i, chunk c in 0..7:
//   c==0: d={0(diag),1,2,3} (+32 if i<32); c>0: d={4c..4c+3}; j=(i+d)&63.
// MX-scaled fp8 K=128 MFMA (unit scales). A-tile is invariant for the whole block:
// each wave hoists its 4 mi-fragments x full K=256 into 64 VGPRs (areg[4][2]) ONCE
// after the A-stage barrier, eliminating the per-chunk-step A ds_reads (halves LDS
// read traffic; simsum becomes MFMA-pipe-bound). Main loop restructured over tiles t
// with STATIC K-half index so areg indexing never goes to scratch (rule #20).
// B staged in K=128 halves into ping-pong buffers; stage(next) issued BEFORE compute.
// LDS 32K(A) + 2x16K(B) + 2K = 66KB -> 2 blocks/CU; grid (64,8)=512 = exactly 2/CU.
__global__ __launch_bounds__(256, 2) void simsum_kernel(
    const unsigned char* __restrict__ reps,
    float* __restrict__ rowscratch,   // [64][8][128]
    float* __restrict__ colscratch) { // [64][32][128]
  __shared__ __align__(16) unsigned char Alds[128 * 256];     // 32 KB
  __shared__ __align__(16) unsigned char Blds[2][128 * 128];  // 2 x 16 KB
  __shared__ float colred[2][256];                            // 2 KB

  const int tid  = threadIdx.x;
  const int lane = tid & 63;
  const int wave = tid >> 6;
  const int wm = wave >> 1, wn = wave & 1;   // 2x2 wave grid
  const int quad = lane >> 4;                // 0..3
  const int l16  = lane & 15;
  const int itile = blockIdx.x;              // row tile 0..63
  const int chunk = blockIdx.y;              // distance chunk 0..7
  const int rowBase = itile * 128;
  const char* gbase = (const char*)reps;
  const bool diaghere = (chunk == 0);

  // ---- stage A tile (once): rows [rowBase,+128), 256B/row = 16 16B-chunks.
  // LDS 16B-slot (row,k16) holds global k16' = (k16&8)|((k16^row)&7)  [XOR low3 swizzle]
  {
    const int r0 = tid >> 4;                                   // 0..15
    const int src = (tid & 8) | ((tid ^ (tid >> 4)) & 7);      // swizzled source chunk
    const char* g0 = gbase + (rowBase + r0) * ZDIM + src * 16; // +p*16 rows => +p*4096
    char* l0 = (char*)Alds + (wave << 10);                     // +p*4096
    #pragma unroll
    for (int p = 0; p < 8; ++p)
      async_load16(g0 + p * 16 * ZDIM, l0 + p * 4096);
  }

  int doff[4];
  int noff;
  if (diaghere) {
    doff[0] = 1; doff[1] = 2; doff[2] = 3; doff[3] = 32;
    noff = (itile < 32) ? 4 : 3;
  } else {
    doff[0] = chunk * 4; doff[1] = chunk * 4 + 1;
    doff[2] = chunk * 4 + 2; doff[3] = chunk * 4 + 3;
    noff = 4;
  }

  // stage B (tile t_, k-half c_): rows [jt*128,+128), k in [c_*128,+128).
  // 128B/row = 8 16B-slots, slot s holds global chunk s ^ (row&7).
#define STAGE_B2(t_, c_) do {                                                   \
    const int jt_ = (itile + doff[t_]) & 63;                                    \
    const int r0_ = tid >> 3;                              /* 0..31 */          \
    const int src_ = (tid ^ (tid >> 3)) & 7;                                    \
    const char* g0_ = gbase + (jt_ * 128 + r0_) * ZDIM + (c_) * 128 + src_ * 16;\
    char* l0_ = (char*)Blds[c_] + (wave << 10);                                 \
    _Pragma("unroll")                                                           \
    for (int p_ = 0; p_ < 4; ++p_)                                              \
      async_load16(g0_ + p_ * 32 * ZDIM, l0_ + p_ * 4096);                      \
  } while (0)

  // hoist this wave's A operand (4 mi-frags x K=256) from Alds into 64 VGPRs
  i32x8 areg[4][2];
#define LOAD_AREG() do {                                                        \
    _Pragma("unroll")                                                           \
    for (int mi = 0; mi < 4; ++mi) {                                            \
      const int m_ = wm * 64 + mi * 16 + l16;                                   \
      _Pragma("unroll")                                                         \
      for (int cc = 0; cc < 2; ++cc) {                                          \
        _Pragma("unroll")                                                       \
        for (int ws = 0; ws < 4; ++ws) {                                        \
          const int o_ = cc * 16 + ws * 4 + quad;                               \
          const int k16_ = o_ >> 1, half_ = (o_ & 1) * 8;                       \
          const int sw_ = (k16_ & 8) | ((k16_ ^ m_) & 7);                       \
          const i32x2 tt_ = *(const i32x2*)((const char*)Alds + m_ * 256 +      \
                                            sw_ * 16 + half_);                  \
          areg[mi][cc][2 * ws] = tt_.x; areg[mi][cc][2 * ws + 1] = tt_.y;       \
        }                                                                       \
      }                                                                         \
    }                                                                           \
  } while (0)

  float rowpart[16];
  #pragma unroll
  for (int i = 0; i < 16; ++i) rowpart[i] = 0.0f;
  const f32x4 zero4 = {0.0f, 0.0f, 0.0f, 0.0f};

  // ---- prologue: diag tile (if any) computed while stage(0,0) is in flight ----
  if (diaghere) {
    __syncthreads();                  // drain A
    STAGE_B2(0, 0);                   // covered by the diag compute below
    LOAD_AREG();
    f32x4 acc[4][4];
    #pragma unroll
    for (int mi = 0; mi < 4; ++mi)
      #pragma unroll
      for (int ni = 0; ni < 4; ++ni) acc[mi][ni] = zero4;
    #pragma unroll
    for (int h = 0; h < 2; ++h) {     // 2 K=128 passes, B operand from Alds
      i32x8 bfrag[4];
      #pragma unroll
      for (int ni = 0; ni < 4; ++ni) {
        const int n = wn * 64 + ni * 16 + l16;
        #pragma unroll
        for (int ws = 0; ws < 4; ++ws) {
          const int o = h * 16 + ws * 4 + quad;
          const int k16 = o >> 1, half = (o & 1) * 8;
          const int sw = (k16 & 8) | ((k16 ^ n) & 7);
          const i32x2 t = *(const i32x2*)((const char*)Alds + n * 256 + sw * 16 + half);
          bfrag[ni][2 * ws] = t.x; bfrag[ni][2 * ws + 1] = t.y;
        }
      }
      #pragma unroll
      for (int mi = 0; mi < 4; ++mi)
        #pragma unroll
        for (int ni = 0; ni < 4; ++ni)
          acc[mi][ni] = __builtin_amdgcn_mfma_scale_f32_16x16x128_f8f6f4(
              areg[mi][h], bfrag[ni], acc[mi][ni], 0, 0,
              0, SCALE_ONE, 0, SCALE_ONE);
    }
    // diag epilogue: rows only, self-masked (regs only, no LDS, no barrier)
    #pragma unroll
    for (int mi = 0; mi < 4; ++mi)
      #pragma unroll
      for (int r = 0; r < 4; ++r) {
        const int grow = rowBase + wm * 64 + mi * 16 + quad * 4 + r;
        float s = 0.0f;
        #pragma unroll
        for (int ni = 0; ni < 4; ++ni) {
          const int gcol = rowBase + wn * 64 + ni * 16 + l16;
          const float e = exp2f((acc[mi][ni][r] - 1.0f) * EXP_SCALE);
          if (grow != gcol) s += e;
        }
        rowpart[mi * 4 + r] += s;
      }
    __syncthreads();                  // drain stage(0,0)
  } else {
    STAGE_B2(0, 0);
    __syncthreads();                  // drain A + stage(0,0)
    LOAD_AREG();
  }

  // one K=128 MFMA pass: A from areg[.][CC], B from Blds[CC]. CC is compile-time.
#define COMPUTE_HALF(CC) do {                                                   \
    i32x8 bfrag[4];                                                             \
    _Pragma("unroll")                                                           \
    for (int ni = 0; ni < 4; ++ni) {                                            \
      const int n = wn * 64 + ni * 16 + l16;                                    \
      _Pragma("unroll")                                                         \
      for (int ws = 0; ws < 4; ++ws) {                                          \
        const int ol = ws * 4 + quad;           /* chunk-local octet */         \
        const int k16l = ol >> 1, halfl = (ol & 1) * 8;                         \
        const int sw = (k16l ^ n) & 7;                                          \
        const i32x2 t = *(const i32x2*)((const char*)Blds[CC] + n * 128 +       \
                                        sw * 16 + halfl);                       \
        bfrag[ni][2 * ws] = t.x; bfrag[ni][2 * ws + 1] = t.y;                   \
      }                                                                         \
    }                                                                           \
    _Pragma("unroll")                                                           \
    for (int mi = 0; mi < 4; ++mi)                                              \
      _Pragma("unroll")                                                         \
      for (int ni = 0; ni < 4; ++ni)                                            \
        acc[mi][ni] = __builtin_amdgcn_mfma_scale_f32_16x16x128_f8f6f4(         \
            areg[mi][CC], bfrag[ni], acc[mi][ni], 0, 0,                         \
            0, SCALE_ONE, 0, SCALE_ONE);                                        \
  } while (0)

  // ---- pipelined main loop over tiles (two K-halves each, static indices) ----
  f32x4 acc[4][4];
  for (int t = 0; t < noff; ++t) {
    const int d = doff[t];
    const int jtile = (itile + d) & 63;

    // half 0: stage this tile's half 1, compute half 0 from Blds[0]
    STAGE_B2(t, 1);
    #pragma unroll
    for (int mi = 0; mi < 4; ++mi)
      #pragma unroll
      for (int ni = 0; ni < 4; ++ni) acc[mi][ni] = zero4;
    COMPUTE_HALF(0);
    __syncthreads();   // drains stage(t,1); Blds[0] reads done before next overwrite

    // half 1: stage next tile's half 0, compute half 1 from Blds[1]
    if (t + 1 < noff) STAGE_B2(t + 1, 0);
    COMPUTE_HALF(1);

    // tile complete: exp epilogue. Rows -> rowpart; cols -> colred[t&1] -> colscratch.
    {
      float colpart[4] = {0.0f, 0.0f, 0.0f, 0.0f};
      #pragma unroll
      for (int mi = 0; mi < 4; ++mi)
        #pragma unroll
        for (int r = 0; r < 4; ++r) {
          float s = 0.0f;
          #pragma unroll
          for (int ni = 0; ni < 4; ++ni) {
            const float e = exp2f((acc[mi][ni][r] - 1.0f) * EXP_SCALE);
            s += e;
            colpart[ni] += e;
          }
          rowpart[mi * 4 + r] += s;
        }
      #pragma unroll
      for (int ni = 0; ni < 4; ++ni) {
        float v = colpart[ni];
        v += __shfl_xor(v, 16, 64);   // reduce across the 4 quads (frag rows)
        v += __shfl_xor(v, 32, 64);
        if (quad == 0) colred[t & 1][wm * 128 + wn * 64 + ni * 16 + l16] = v;
      }
      __syncthreads();   // drains stage(t+1,0); colred visible; Blds[1] free
      if (tid < 128)
        colscratch[(jtile * 32 + (d - 1)) * 128 + tid] =
            colred[t & 1][tid] + colred[t & 1][128 + tid];
      // next write to colred[t&1] is 2 barriers away (tile t+2) — safe without barrier
    }
  }

  // ---- row partials: shfl over 16 col-lanes, merge wn-halves via LDS (they cover the
  // SAME rows — per-wave plain stores would race), one store per row ----
  #pragma unroll
  for (int i = 0; i < 16; ++i) {
    float v = rowpart[i];
    v += __shfl_xor(v, 1, 64);
    v += __shfl_xor(v, 2, 64);
    v += __shfl_xor(v, 4, 64);
    v += __shfl_xor(v, 8, 64);
    rowpart[i] = v;
  }
  __syncthreads();
  if (l16 == 0) {
    #pragma unroll
    for (int mi = 0; mi < 4; ++mi)
      #pragma unroll
      for (int r = 0; r < 4; ++r)
        colred[0][wn * 128 + wm * 64 + mi * 16 + quad * 4 + r] = rowpart[mi * 4 + r];
  }
  __syncthreads();
  if (tid < 128)
    rowscratch[(itile * 8 + chunk) * 128 + tid] = colred[0][tid] + colred[0][128 + tid];
#undef STAGE_B2
#undef LOAD_AREG
#undef COMPUTE_HALF
}

// ---------------- Kernel C: fully-parallel gather of row partials --------------------
// 512 blocks x 256 threads: 16 rows/block, 16 lanes/row, each lane loads <=3 partials
// (fully unrolled, independent loads), 4-step shfl reduce per row, log, block reduce.
__global__ __launch_bounds__(256) void reduce_kernel(
    const float* __restrict__ rowscratch, const float* __restrict__ colscratch,
    const float* __restrict__ pos, float* __restrict__ out) {
  const int bid = blockIdx.x;              // 0..511
  const int tid = threadIdx.x;
  const int j  = bid * 16 + (tid >> 4);    // global row 0..8191 (16 rows share one jt)
  const int k  = tid & 15;                 // slice within row
  const int jt = j >> 7, o = j & 127;
  const int ns = (jt < 32) ? 31 : 32;      // jt<32: d=32 pair arrived via rowscratch side
  const int limit = 8 + ns;                // 39 or 40 partials per row
  float s = 0.0f;
  #pragma unroll
  for (int step = 0; step < 3; ++step) {
    const int idx = k + step * 16;
    if (idx < limit)
      s += (idx < 8) ? rowscratch[(jt * 8 + idx) * 128 + o]
                     : colscratch[(jt * 32 + (idx - 8)) * 128 + o];
  }
  s += __shfl_xor(s, 1, 64);
  s += __shfl_xor(s, 2, 64);
  s += __shfl_xor(s, 4, 64);
  s += __shfl_xor(s, 8, 64);               // all 16 lanes of the group now hold row sum
  float v = (k == 0) ? logf(s) * (1.0f / (float)TWO_N) : 0.0f;
  if (tid < 8) v -= pos[bid * 8 + tid] * (INV_T / (float)N_ROWS);
  #pragma unroll
  for (int m = 1; m < 64; m <<= 1) v += __shfl_xor(v, m, 64);
  __shared__ float red[4];
  if ((tid & 63) == 0) red[tid >> 6] = v;
  __syncthreads();
  if (tid == 0) atomicAdd(out, red[0] + red[1] + red[2] + red[3]);
}

extern "C" void kernel_launch(void* const* d_in, const int* in_sizes, int n_in,
                              void* d_out, int out_size, void* d_ws, size_t ws_size,
                              hipStream_t stream) {
  const float* z1 = (const float*)d_in[0];
  const float* z2 = (const float*)d_in[1];
  char* ws = (char*)d_ws;
  unsigned char* reps = (unsigned char*)ws;                // 8192*256 = 2 MB fp8
  size_t off = (size_t)TWO_N * ZDIM;
  float* pos = (float*)(ws + off);        off += N_ROWS * 4;        // 16 KB
  float* rowscratch = (float*)(ws + off); off += 64 * 8 * 128 * 4;  // 256 KB
  float* colscratch = (float*)(ws + off); off += 64 * 32 * 128 * 4; // 1 MB

  normalize_kernel<<<1024, 256, 0, stream>>>(z1, z2, reps, pos, (float*)d_out);
  simsum_kernel<<<dim3(64, 8), 256, 0, stream>>>(reps, rowscratch, colscratch);
  reduce_kernel<<<512, 256, 0, stream>>>(rowscratch, colscratch, pos, (float*)d_out);
}